// Round 9
// baseline (131.575 us; speedup 1.0000x reference)
//
#include <hip/hip_runtime.h>
#include <hip/hip_bf16.h>
#include <math.h>

// CMDTLoss: supervised-contrastive loss on FFT'd features.
// Plancherel: Re(FFT(u)·conj(FFT(v))) = D*(u·v), ||FFT(u)|| = sqrt(D)*||u||
// => cosine sim of FFT'd rows == cosine sim of raw rows. Collapses to:
// sim = (normalized F F^T)/tau -> masked log-prob reduction.
//
// R9: single fused kernel (prep -> GRID BARRIER -> 528 fp8 band-pair GEMM
// tiles -> GRID BARRIER -> final) using a MANUAL device-scope atomic
// barrier: R8 showed hipLaunchCooperativeKernel is not graph-capturable in
// this harness (kernel never ran). Co-residency by construction: 264 WGs x
// 64KB LDS = 2 WGs/CU -> 512-WG capacity >= 264. Tiny init kernel zeroes
// the barrier words (ws is 0xAA-poisoned each iteration). Purpose: remove
// all inter-dispatch structure and make the pipeline ONE dispatch so its
// duration/counters are finally visible past the 43.5us harness fills.

#define NROWS 4096
#define DDIM  512
#define BAND  128
#define NBAND (NROWS / BAND)             // 32
#define NPAIR (NBAND * (NBAND + 1) / 2)  // 528
#define NWG   264                        // x2 tiles each = 528
#define NSTEP 16

typedef __attribute__((ext_vector_type(4))) float floatx4;

__device__ inline long f8pack(float v0, float v1, float v2, float v3,
                              float v4, float v5, float v6, float v7) {
    int lo = 0, hi = 0;
    lo = __builtin_amdgcn_cvt_pk_fp8_f32(v0, v1, lo, false);
    lo = __builtin_amdgcn_cvt_pk_fp8_f32(v2, v3, lo, true);
    hi = __builtin_amdgcn_cvt_pk_fp8_f32(v4, v5, hi, false);
    hi = __builtin_amdgcn_cvt_pk_fp8_f32(v6, v7, hi, true);
    return ((long)(unsigned)lo) | ((long)hi << 32);
}

__device__ inline float dpp_add16(float v) {
    v += __int_as_float(__builtin_amdgcn_update_dpp(
        0, __float_as_int(v), 0xB1, 0xF, 0xF, true));   // quad_perm xor1
    v += __int_as_float(__builtin_amdgcn_update_dpp(
        0, __float_as_int(v), 0x4E, 0xF, 0xF, true));   // quad_perm xor2
    v += __int_as_float(__builtin_amdgcn_update_dpp(
        0, __float_as_int(v), 0x141, 0xF, 0xF, true));  // row_half_mirror
    v += __int_as_float(__builtin_amdgcn_update_dpp(
        0, __float_as_int(v), 0x140, 0xF, 0xF, true));  // row_mirror
    return v;
}

__global__ __launch_bounds__(64) void init_bar(int* __restrict__ bar) {
    if (threadIdx.x < 8) bar[threadIdx.x] = 0;
}

// Manual grid barrier: release-fence, arrive, spin (thread 0), acquire-fence.
// Requires all NWG workgroups co-resident (2/CU capacity vs 264/256 CUs).
__device__ inline void gbar(int* __restrict__ bar, int slot) {
    __syncthreads();
    if (threadIdx.x == 0) {
        __threadfence();  // release: drain + L2 writeback (device scope)
        atomicAdd(&bar[slot], 1);
        while (__hip_atomic_load(&bar[slot], __ATOMIC_RELAXED,
                                 __HIP_MEMORY_SCOPE_AGENT) < NWG)
            __builtin_amdgcn_s_sleep(2);
        __threadfence();  // acquire: invalidate L1/L2 before consuming
    }
    __syncthreads();
}

__global__ __launch_bounds__(256, 2) void fused_all(
    const float* __restrict__ F, const int* __restrict__ labels,
    long* __restrict__ Fq, float* __restrict__ invn,
    float* __restrict__ S, float* __restrict__ P,
    int* __restrict__ hist, int* __restrict__ bar,
    float* __restrict__ out) {
    __shared__ long Asl[BAND * 64];  // 64 KB; reused by every phase
    const int wg = blockIdx.x;
    const int tid = threadIdx.x;
    const int w = tid >> 6, lane = tid & 63;
    const int lrow = lane & 15, lquad = lane >> 4;

    // ---- Phase 1: prep (fp8 frag-major convert, norms, zero S/P, hist) ----
    if (wg < NROWS / 16) {
        const int g = wg;
        const int row = g * 16 + (lane & 15);
        const int koff = ((lane >> 4) & 3) * 8;
        float ss = 0.f;
#pragma unroll
        for (int c = 0; c < 4; ++c) {
            const int s = c * 4 + w;
            const int k = s * 32 + koff;
            const float4* src = (const float4*)(F + (size_t)row * DDIM + k);
            float4 a = src[0], b = src[1];
            ss += a.x * a.x + a.y * a.y + a.z * a.z + a.w * a.w
                + b.x * b.x + b.y * b.y + b.z * b.z + b.w * b.w;
            Fq[(size_t)(g * 16 + s) * 64 + lane] =
                f8pack(a.x, a.y, a.z, a.w, b.x, b.y, b.z, b.w);
        }
        ss += __shfl_xor(ss, 16, 64);
        ss += __shfl_xor(ss, 32, 64);
        float* rs = (float*)Asl;  // [4][16]
        if (lane < 16) rs[w * 16 + lane] = ss;
        __syncthreads();
        if (tid < 16) {
            float tot = rs[tid] + rs[16 + tid] + rs[32 + tid] + rs[48 + tid];
            int r = g * 16 + tid;
            invn[r] = rsqrtf(tot) * 3.16227766017f;  // * sqrt(1/tau)
            S[r] = 0.f;
            P[r] = 0.f;
        }
        if (g == 0) {
            int* h = (int*)Asl + 64;  // past rs region
            __syncthreads();
            if (tid < 128) h[tid] = 0;
            __syncthreads();
            for (int i = tid; i < NROWS; i += 256) atomicAdd(&h[labels[i]], 1);
            __syncthreads();
            if (tid < 128) hist[tid] = h[tid];
        }
    }
    gbar(bar, 0);

    // ---- Phase 2: 2 band-pair GEMM tiles per WG ---------------------------
#pragma unroll 1
    for (int rep = 0; rep < 2; ++rep) {
        const int wid = wg + rep * NWG;  // 0..527
        int bi = 0;
        while ((bi + 1) * NBAND - (bi + 1) * bi / 2 <= wid) ++bi;
        const int bj = bi + (wid - (bi * NBAND - bi * (bi - 1) / 2));
        const bool diag = (bi == bj);
        const int ib = bi * BAND, jb = bj * BAND;

        __syncthreads();  // previous phase fully done with Asl
        {
            const long* src = Fq + (size_t)bi * 8192;
#pragma unroll
            for (int r = 0; r < 16; ++r) {
                __builtin_amdgcn_global_load_lds(
                    (const __attribute__((address_space(1))) unsigned int*)
                        (src + r * 512 + (size_t)tid * 2),
                    (__attribute__((address_space(3))) unsigned int*)
                        (Asl + r * 512 + tid * 2),
                    16, 0, 0);
            }
        }
        __syncthreads();

        floatx4 acc[8][2];
#pragma unroll
        for (int mi = 0; mi < 8; ++mi) {
            acc[mi][0] = (floatx4){0.f, 0.f, 0.f, 0.f};
            acc[mi][1] = (floatx4){0.f, 0.f, 0.f, 0.f};
        }

        // B fragments direct from global, coalesced 512B; depth-3 prefetch.
        const long* pB0 = Fq + (size_t)(bj * 8 + w * 2) * 1024 + lane;
        const long* pB1 = pB0 + 1024;
        long br0[3], br1[3];
        br0[0] = pB0[0];   br1[0] = pB1[0];
        br0[1] = pB0[64];  br1[1] = pB1[64];
        br0[2] = pB0[128]; br1[2] = pB1[128];

#pragma unroll
        for (int ks = 0; ks < NSTEP; ++ks) {
            const int cur = ks % 3;
            const long b0 = br0[cur], b1 = br1[cur];
            if (ks + 3 < NSTEP) {
                br0[cur] = pB0[(ks + 3) * 64];
                br1[cur] = pB1[(ks + 3) * 64];
            }
            long a[8];
#pragma unroll
            for (int mi = 0; mi < 8; ++mi)
                a[mi] = Asl[(mi * 16 + ks) * 64 + lane];
#pragma unroll
            for (int mi = 0; mi < 8; ++mi) {
                acc[mi][0] = __builtin_amdgcn_mfma_f32_16x16x32_fp8_fp8(
                    a[mi], b0, acc[mi][0], 0, 0, 0);
                acc[mi][1] = __builtin_amdgcn_mfma_f32_16x16x32_fp8_fp8(
                    a[mi], b1, acc[mi][1], 0, 0, 0);
            }
        }

        // Epilogue. C/D layout: col = lrow, row = lquad*4 + reg.
        __syncthreads();
        float* er = (float*)Asl;
        float* pr = er + 128;
        float* ec = pr + 128;
        float* pc = ec + 128;
        ((float*)Asl)[tid] = 0.f;
        ((float*)Asl)[tid + 256] = 0.f;
        __syncthreads();

        float inB[2];
        int lB[2];
#pragma unroll
        for (int ni = 0; ni < 2; ++ni) {
            int j = jb + (w * 2 + ni) * 16 + lrow;
            inB[ni] = invn[j];
            lB[ni] = labels[j];
        }

        float ecol[2] = {0.f, 0.f}, pcol[2] = {0.f, 0.f};
#pragma unroll
        for (int mi = 0; mi < 8; ++mi) {
#pragma unroll
            for (int r = 0; r < 4; ++r) {
                const int il = mi * 16 + lquad * 4 + r;
                const int i = ib + il;
                const float inA = invn[i];
                const int lA = labels[i];
                float es = 0.f, ps = 0.f;
#pragma unroll
                for (int ni = 0; ni < 2; ++ni) {
                    const int j = jb + (w * 2 + ni) * 16 + lrow;
                    float sim = acc[mi][ni][r] * inA * inB[ni];
                    float e = __expf(sim);
                    float pm = (lA == lB[ni]) ? sim : 0.f;
                    if (diag && i == j) { e = 0.f; pm = 0.f; }
                    es += e; ps += pm;
                    ecol[ni] += e; pcol[ni] += pm;
                }
                es = dpp_add16(es);
                ps = dpp_add16(ps);
                if (lrow == 0) {
                    atomicAdd(&er[il], es);
                    atomicAdd(&pr[il], ps);
                }
            }
        }
#pragma unroll
        for (int ni = 0; ni < 2; ++ni) {
            float e = ecol[ni], p = pcol[ni];
            e += __shfl_xor(e, 16, 64);
            e += __shfl_xor(e, 32, 64);
            p += __shfl_xor(p, 16, 64);
            p += __shfl_xor(p, 32, 64);
            if (lquad == 0) {
                atomicAdd(&ec[(w * 2 + ni) * 16 + lrow], e);
                atomicAdd(&pc[(w * 2 + ni) * 16 + lrow], p);
            }
        }
        __syncthreads();
        if (tid < 128) {
            atomicAdd(&S[ib + tid], er[tid]);
            atomicAdd(&P[ib + tid], pr[tid]);
        } else if (!diag) {
            atomicAdd(&S[jb + tid - 128], ec[tid - 128]);
            atomicAdd(&P[jb + tid - 128], pc[tid - 128]);
        }
    }
    gbar(bar, 1);

    // ---- Phase 3: final reduction (WG 0) ----------------------------------
    if (wg == 0) {
        float local = 0.f;
        for (int i = tid; i < NROWS; i += 256) {
            float cnt = (float)(hist[labels[i]] - 1);
            local += (P[i] - cnt * logf(S[i])) / (cnt + 1e-8f);
        }
#pragma unroll
        for (int m = 1; m < 64; m <<= 1) local += __shfl_xor(local, m, 64);
        float* red = (float*)Asl;
        __syncthreads();
        if ((tid & 63) == 0) red[w] = local;
        __syncthreads();
        if (tid == 0)
            out[0] = -(red[0] + red[1] + red[2] + red[3]) / (float)NROWS;
    }
}

extern "C" void kernel_launch(void* const* d_in, const int* in_sizes, int n_in,
                              void* d_out, int out_size, void* d_ws, size_t ws_size,
                              hipStream_t stream) {
    const float* F = (const float*)d_in[0];
    const int* labels = (const int*)d_in[1];
    float* out = (float*)d_out;

    // ws: Fq[2MB fp8 frag-major] | invn[16KB] | S[16KB] | P[16KB] | hist | bar
    long* Fq = (long*)d_ws;
    float* invn = (float*)((char*)d_ws + (size_t)NROWS * DDIM);
    float* S = invn + NROWS;
    float* P = S + NROWS;
    int* hist = (int*)(P + NROWS);
    int* bar = hist + 128;

    init_bar<<<dim3(1), dim3(64), 0, stream>>>(bar);
    fused_all<<<dim3(NWG), dim3(256), 0, stream>>>(
        F, labels, Fq, invn, S, P, hist, bar, out);
}

// Round 10
// 106.345 us; speedup vs baseline: 1.2372x; 1.2372x over previous
//
#include <hip/hip_runtime.h>
#include <hip/hip_bf16.h>
#include <math.h>

// CMDTLoss: supervised-contrastive loss on FFT'd features.
// Plancherel: Re(FFT(u)·conj(FFT(v))) = D*(u·v), ||FFT(u)|| = sqrt(D)*||u||
// => cosine sim of FFT'd rows == cosine sim of raw rows. Collapses to:
// sim = (normalized F F^T)/tau -> masked log-prob reduction.
//
// R10: the untested design-matrix cell -- 4 waves/SIMD + spill-free +
// barrier-free + coalesced. R9's counters (MfmaUtil 4%, VALU 6%, HBM 3%)
// proved >90% stall at 1 wave/SIMD; R2 had 4/SIMD but barrier-coupled
// staging; R5 spilled; R6/R7 were LDS-capped at 2/SIMD. Here: full-matrix
// 4096 x (64x64) wave-tiles = 4096 waves = exactly 4/SIMD, fp8 frag-major
// (512B coalesced loads, Fq=2MB fits every XCD's L2), no LDS, no barriers,
// ~95 VGPR (no spill), row-sum-only epilogue.

#define NROWS 4096
#define DDIM  512
#define NBG   (NROWS / 64)   // 64 row-groups of 64 -> 4096 full-matrix tiles
#define NSTEP 16

typedef __attribute__((ext_vector_type(4))) float floatx4;

__device__ inline long f8pack(float v0, float v1, float v2, float v3,
                              float v4, float v5, float v6, float v7) {
    int lo = 0, hi = 0;
    lo = __builtin_amdgcn_cvt_pk_fp8_f32(v0, v1, lo, false);
    lo = __builtin_amdgcn_cvt_pk_fp8_f32(v2, v3, lo, true);
    hi = __builtin_amdgcn_cvt_pk_fp8_f32(v4, v5, hi, false);
    hi = __builtin_amdgcn_cvt_pk_fp8_f32(v6, v7, hi, true);
    return ((long)(unsigned)lo) | ((long)hi << 32);
}

__device__ inline float dpp_add16(float v) {
    v += __int_as_float(__builtin_amdgcn_update_dpp(
        0, __float_as_int(v), 0xB1, 0xF, 0xF, true));   // quad_perm xor1
    v += __int_as_float(__builtin_amdgcn_update_dpp(
        0, __float_as_int(v), 0x4E, 0xF, 0xF, true));   // quad_perm xor2
    v += __int_as_float(__builtin_amdgcn_update_dpp(
        0, __float_as_int(v), 0x141, 0xF, 0xF, true));  // row_half_mirror
    v += __int_as_float(__builtin_amdgcn_update_dpp(
        0, __float_as_int(v), 0x140, 0xF, 0xF, true));  // row_mirror
    return v;
}

// Prep: fp32 F -> fp8 e4m3 FRAGMENT-MAJOR + fp32 norms + zero S/P + hist.
// Fragment-major long-unit index: (g*16 + s)*64 + l, unit holds row
// g*16+(l&15), k = s*32 + ((l>>4)&3)*8 .. +7  (MFMA 16x16x32 fp8 operand
// layout). Verified exact in R7/R9 (absmax 0.0).
__global__ __launch_bounds__(256) void prep_kernel(
    const float* __restrict__ F, const int* __restrict__ labels,
    long* __restrict__ Fq, float* __restrict__ invn,
    float* __restrict__ S, float* __restrict__ P, int* __restrict__ hist) {
    const int g = blockIdx.x, t = threadIdx.x;
    const int l = t & 63, w = t >> 6;
    const int row = g * 16 + (l & 15);
    const int koff = ((l >> 4) & 3) * 8;
    float ss = 0.f;
#pragma unroll
    for (int c = 0; c < 4; ++c) {
        const int s = c * 4 + w;
        const int k = s * 32 + koff;
        const float4* src = (const float4*)(F + (size_t)row * DDIM + k);
        float4 a = src[0], b = src[1];
        ss += a.x * a.x + a.y * a.y + a.z * a.z + a.w * a.w
            + b.x * b.x + b.y * b.y + b.z * b.z + b.w * b.w;
        Fq[(size_t)(g * 16 + s) * 64 + l] =
            f8pack(a.x, a.y, a.z, a.w, b.x, b.y, b.z, b.w);
    }
    ss += __shfl_xor(ss, 16, 64);
    ss += __shfl_xor(ss, 32, 64);
    __shared__ float rs[4][16];
    if (l < 16) rs[w][l] = ss;
    __syncthreads();
    if (t < 16) {
        float tot = rs[0][t] + rs[1][t] + rs[2][t] + rs[3][t];
        int r = g * 16 + t;
        invn[r] = rsqrtf(tot) * 3.16227766017f;  // * sqrt(1/TEMPERATURE)
        S[r] = 0.f;
        P[r] = 0.f;
    }
    if (g == 0) {
        __shared__ int h[128];
        if (t < 128) h[t] = 0;
        __syncthreads();
        for (int i = t; i < NROWS; i += 256) atomicAdd(&h[labels[i]], 1);
        __syncthreads();
        if (t < 128) hist[t] = h[t];
    }
}

// Full-matrix wave-per-tile GEMM. Grid 1024 x 256 = 4096 waves (4/SIMD).
// Wave wid -> tile (bi = wid>>6, bj = wid&63), 64x64 output, row sums only.
__global__ __launch_bounds__(256, 4) void gemm_kernel(
    const long* __restrict__ Fq, const float* __restrict__ invn,
    const int* __restrict__ labels,
    float* __restrict__ S, float* __restrict__ P) {
    const int wid = blockIdx.x * 4 + (threadIdx.x >> 6);
    const int lane = threadIdx.x & 63;
    const int lrow = lane & 15, lquad = lane >> 4;
    const int bi = wid >> 6, bj = wid & 63;

    // fragment-major: group g's step-s fragment at long-unit (g*16+s)*64+lane
    const long* pA = Fq + (size_t)(bi * 4) * 1024 + lane;
    const long* pB = Fq + (size_t)(bj * 4) * 1024 + lane;

    floatx4 acc[4][4];
#pragma unroll
    for (int mi = 0; mi < 4; ++mi)
#pragma unroll
        for (int ni = 0; ni < 4; ++ni) acc[mi][ni] = (floatx4){0.f, 0.f, 0.f, 0.f};

#pragma unroll
    for (int ks = 0; ks < NSTEP; ++ks) {
        long av[4], bv[4];
#pragma unroll
        for (int mi = 0; mi < 4; ++mi) av[mi] = pA[mi * 1024 + ks * 64];
#pragma unroll
        for (int ni = 0; ni < 4; ++ni) bv[ni] = pB[ni * 1024 + ks * 64];
#pragma unroll
        for (int mi = 0; mi < 4; ++mi)
#pragma unroll
            for (int ni = 0; ni < 4; ++ni)
                acc[mi][ni] = __builtin_amdgcn_mfma_f32_16x16x32_fp8_fp8(
                    av[mi], bv[ni], acc[mi][ni], 0, 0, 0);
    }

    // Epilogue: row sums only (full matrix). C/D: col=lrow, row=lquad*4+reg.
    float inB[4];
    int lB[4];
#pragma unroll
    for (int ni = 0; ni < 4; ++ni) {
        int j = bj * 64 + ni * 16 + lrow;
        inB[ni] = invn[j];
        lB[ni] = labels[j];
    }
#pragma unroll
    for (int mi = 0; mi < 4; ++mi) {
#pragma unroll
        for (int r = 0; r < 4; ++r) {
            const int i = bi * 64 + mi * 16 + lquad * 4 + r;
            const float inA = invn[i];
            const int lA = labels[i];
            float es = 0.f, ps = 0.f;
#pragma unroll
            for (int ni = 0; ni < 4; ++ni) {
                const int j = bj * 64 + ni * 16 + lrow;
                float sim = acc[mi][ni][r] * inA * inB[ni];
                float e = __expf(sim);
                float pm = (lA == lB[ni]) ? sim : 0.f;
                if (bi == bj && i == j) { e = 0.f; pm = 0.f; }
                es += e;
                ps += pm;
            }
            es = dpp_add16(es);
            ps = dpp_add16(ps);
            if (lrow == 0) {
                atomicAdd(&S[i], es);
                atomicAdd(&P[i], ps);
            }
        }
    }
}

__global__ __launch_bounds__(256) void final_kernel(
    const float* __restrict__ S, const float* __restrict__ P,
    const int* __restrict__ labels, const int* __restrict__ hist,
    float* __restrict__ out) {
    float local = 0.f;
    for (int i = threadIdx.x; i < NROWS; i += 256) {
        float cnt = (float)(hist[labels[i]] - 1);
        local += (P[i] - cnt * logf(S[i])) / (cnt + 1e-8f);
    }
#pragma unroll
    for (int m = 1; m < 64; m <<= 1) local += __shfl_xor(local, m, 64);
    __shared__ float red[4];
    int wave = threadIdx.x >> 6;
    if ((threadIdx.x & 63) == 0) red[wave] = local;
    __syncthreads();
    if (threadIdx.x == 0)
        out[0] = -(red[0] + red[1] + red[2] + red[3]) / (float)NROWS;
}

extern "C" void kernel_launch(void* const* d_in, const int* in_sizes, int n_in,
                              void* d_out, int out_size, void* d_ws, size_t ws_size,
                              hipStream_t stream) {
    const float* F = (const float*)d_in[0];
    const int* labels = (const int*)d_in[1];
    float* out = (float*)d_out;

    // ws: Fq[2MB fp8 frag-major] | invn[16KB] | S[16KB] | P[16KB] | hist
    long* Fq = (long*)d_ws;
    float* invn = (float*)((char*)d_ws + (size_t)NROWS * DDIM);
    float* S = invn + NROWS;
    float* P = S + NROWS;
    int* hist = (int*)(P + NROWS);

    prep_kernel<<<dim3(NROWS / 16), dim3(256), 0, stream>>>(
        F, labels, Fq, invn, S, P, hist);
    gemm_kernel<<<dim3(NROWS / 64 * NBG / 4), dim3(256), 0, stream>>>(
        Fq, invn, labels, S, P);
    final_kernel<<<dim3(1), dim3(256), 0, stream>>>(S, P, labels, hist, out);
}